// Round 1
// baseline (141.861 us; speedup 1.0000x reference)
//
#include <hip/hip_runtime.h>

#define B_TOT 16384
#define NPAIR (B_TOT*5)        // 81920 (b,chunk) pairs
#define NPT32 (NPAIR/32)       // 2560 pair-tiles of 32 pairs
#define NKG   8                // k-groups of 16 k-tiles (512 k each)
#define KTPG  16               // k-tiles per group
#define KTB   9216             // bytes per A k-tile: 9 frags x 1KB
#define PHB   (2*KTB)          // 18432 B per phase (2 k-tiles)

// fused front-kernel grid split
#define PREP_BLKS 288          // 1152 prep-units / 4 per 256-thr block
#define SIGN_BLKS 320          // 81920 / 256
#define EMBD_BLKS 64           // 16384 / 256

typedef __attribute__((ext_vector_type(8))) short bf16x8;
typedef __attribute__((ext_vector_type(16))) float f32x16;

struct alignas(8) us4 { unsigned short x, y, z, w; };

__device__ inline unsigned short f2bf(float f) {
    unsigned u = __builtin_bit_cast(unsigned, f);
    unsigned r = u + 0x7fffu + ((u >> 16) & 1u);
    return (unsigned short)(r >> 16);
}
__device__ inline float bf2f(unsigned short b) {
    unsigned u = ((unsigned)b) << 16;
    return __builtin_bit_cast(float, u);
}
__device__ inline float max3f(float a, float b, float c) {
    return fmaxf(fmaxf(a, b), c);      // fuses to v_max3_f32
}

// ---------- fused front kernel: kprep + k1_signs + k1_embed --------------------
// Section A (bid < PREP_BLKS): H1 [45][4096] f32 -> Abuf bf16 3-split,
//   32x32x16-frag-major (verified layout). Block blk = kt*9 + s*3 + q : 1KB frag.
//   Lane l: row(k-vocab) = kt*32 + (l&31), h = l>>5;
//     elem j<4:  d = 16s + 4h + j ;  j>=4: d = 16s + 8 + 4h + (j-4). d>=45 -> 0.
// Section B: per-(b,c) sign computation -> Bbuf (chunk c uses only e[6c..6c+5]).
// Section C: per-b full embed -> ebd out + part-2 argmax -> p2vec.
__global__ __launch_bounds__(256) void kfront(
    const int* __restrict__ x,
    const float* __restrict__ lenLUT, const float* __restrict__ ipdLUT,
    const float* __restrict__ S1, const float* __restrict__ H1,
    const float* __restrict__ T1,
    const float* __restrict__ S2, const float* __restrict__ H2,
    const float* __restrict__ T2, const float* __restrict__ LUT2,
    float* __restrict__ out, float* __restrict__ p2vec,
    unsigned short* __restrict__ Abuf, unsigned short* __restrict__ Bbuf) {
    const int bid = blockIdx.x;
    const int tid = threadIdx.x;

    if (bid < PREP_BLKS) {
        // ---- kprep (4 prep-units of 64 lanes per block) ----
        int blk = bid * 4 + (tid >> 6);     // 0..1151
        int kt = blk / 9, rem = blk - kt*9;
        int s = rem / 3, q = rem - s*3;
        int l = tid & 63;
        int h = l >> 5;
        int row = kt*32 + (l & 31);
        unsigned short o[8];
#pragma unroll
        for (int j = 0; j < 8; ++j) {
            int d = 16*s + 4*h + ((j < 4) ? j : (j + 4));
            float v = (d < 45) ? H1[(size_t)d*4096 + row] : 0.f;
            unsigned short bb = 0;
            for (int qq = 0; qq <= q; ++qq) { bb = f2bf(v); v -= bf2f(bb); }  // q uniform per 64-group
            o[j] = bb;
        }
        unsigned short* dst = Abuf + (size_t)blk*512 + l*8;
        *(us4*)(dst)     = us4{o[0], o[1], o[2], o[3]};
        *(us4*)(dst + 4) = us4{o[4], o[5], o[6], o[7]};
        return;
    }

    if (bid < PREP_BLKS + SIGN_BLKS) {
        // ---- k1_signs: one thread per (b,c) pair, p = b*5 + c ----
        int p = (bid - PREP_BLKS) * 256 + tid;   // 0..81919
        int b = p / 5;
        int c = p - b * 5;
        int x0 = x[2*b], x1 = x[2*b+1];
        float e[6];
        const float2* l2 = (const float2*)(lenLUT + (size_t)x0*32 + 6*c);
        const float2* i2 = (const float2*)(ipdLUT + (size_t)x1*32 + 6*c);
#pragma unroll
        for (int t = 0; t < 3; ++t) {
            float2 a = l2[t], d = i2[t];
            e[2*t]   = a.x + d.x;
            e[2*t+1] = a.y + d.y;
        }
        unsigned short sg[48];
#pragma unroll
        for (int t = 0; t < 3; ++t) {
            int c15 = 3*c + t;
#pragma unroll
            for (int k = 0; k < 15; ++k) {
                float a = e[2*t] * S1[(2*c15)*15 + k] + e[2*t+1] * S1[(2*c15+1)*15 + k];
                a = a - T1[c15*15 + k];
                a = a - 1e-4f;
                sg[t*15+k] = (a > 0.f) ? (unsigned short)0x3F80u
                           : ((a < 0.f) ? (unsigned short)0xBF80u : (unsigned short)0);
            }
        }
        sg[45] = 0; sg[46] = 0; sg[47] = 0;
        int P = p >> 5, col = p & 31;
        unsigned short* base = Bbuf + (size_t)P*1536;
#pragma unroll
        for (int s = 0; s < 3; ++s) {
            unsigned short* blk = base + s*512;
            *(us4*)(blk + col*8)          = us4{sg[16*s+0],  sg[16*s+1],  sg[16*s+2],  sg[16*s+3]};
            *(us4*)(blk + col*8 + 4)      = us4{sg[16*s+8],  sg[16*s+9],  sg[16*s+10], sg[16*s+11]};
            *(us4*)(blk + (col+32)*8)     = us4{sg[16*s+4],  sg[16*s+5],  sg[16*s+6],  sg[16*s+7]};
            *(us4*)(blk + (col+32)*8 + 4) = us4{sg[16*s+12], sg[16*s+13], sg[16*s+14], sg[16*s+15]};
        }
        return;
    }

    // ---- k1_embed: per-b full embed row -> ebd out, part-2 -> p2vec ----
    {
        int b = (bid - PREP_BLKS - SIGN_BLKS) * 256 + tid;
        if (b >= B_TOT) return;
        int x0 = x[2*b], x1 = x[2*b+1];
        const float4* l4 = (const float4*)(lenLUT + (size_t)x0*32);
        const float4* i4 = (const float4*)(ipdLUT + (size_t)x1*32);
        float4* o4 = (float4*)(out + (size_t)B_TOT*32 + (size_t)b*32);
        float e30 = 0.f, e31 = 0.f;
#pragma unroll
        for (int j = 0; j < 8; ++j) {
            float4 a = l4[j], c = i4[j];
            float4 sv; sv.x=a.x+c.x; sv.y=a.y+c.y; sv.z=a.z+c.z; sv.w=a.w+c.w;
            o4[j] = sv;
            if (j == 7) { e30 = sv.z; e31 = sv.w; }
        }
        float sb[15];
#pragma unroll
        for (int k = 0; k < 15; ++k) {
            float bb = e30 * S2[k] + e31 * S2[15 + k];
            bb = bb - T2[k];
            sb[k] = (bb > 0.f) ? 1.f : -1.f;       // ==0 -> -1 per jnp.where
        }
        float best = -3.4e38f; int bi = 0;
#pragma unroll
        for (int k2 = 0; k2 < 16; ++k2) {
            float sc = 0.f;
#pragma unroll
            for (int d = 0; d < 15; ++d) sc = fmaf(sb[d], H2[d*16 + k2], sc);
            if (sc > best) { best = sc; bi = k2; }
        }
        const float4* lr = (const float4*)(LUT2 + (size_t)bi*32);
        float4* pv = (float4*)(p2vec + (size_t)b*32);
#pragma unroll
        for (int j = 0; j < 8; ++j) pv[j] = lr[j];
    }
}

// ---------- k2m: R8 structure, occupancy 3 -> 4 blocks/CU ----------
// Block = 4 waves x 2 pt = 8 pt, one k-eighth (16 k-tiles), 2-kt dbuf staging.
// kg = bid&7 -> XCD-pinned A slice.
// LDS 36864 B * 4 = 147456 <= 163840; VGPR 84 <= 128 -> 4 blocks/CU fits.
__global__ __launch_bounds__(256, 4) void k2m(
    const unsigned short* __restrict__ Abuf,
    const unsigned short* __restrict__ Bbuf,
    float* __restrict__ pval, int* __restrict__ pidx) {
    const int bid = blockIdx.x;            // 0..2559
    const int kg = bid & 7;
    const int pg = bid >> 3;               // 0..319
    const int tid = threadIdx.x;
    const int w = tid >> 6, l = tid & 63;
    const int pt0 = pg*8 + w*2;

    __shared__ __align__(16) char lds[2][PHB];    // 2 x 18 KB

    bf16x8 Bf[2][3];
#pragma unroll
    for (int i = 0; i < 2; ++i)
#pragma unroll
        for (int s = 0; s < 3; ++s)
            Bf[i][s] = *(const bf16x8*)(Bbuf + ((size_t)(pt0+i)*3 + s)*512 + l*8);

    // per-pt state: per-reg running max (for index recovery), running (V, bkt)
    float bv16[2][16];
    float V[2] = {-3.4e38f, -3.4e38f};
    int bkt[2] = {0, 0};
#pragma unroll
    for (int i = 0; i < 2; ++i)
#pragma unroll
        for (int r = 0; r < 16; ++r) bv16[i][r] = -3.4e38f;

    const char* Asrc = (const char*)Abuf + (size_t)kg*KTPG*KTB;

    // stage phase 0
#pragma unroll
    for (int r = 0; r < 5; ++r) {
        int idx = tid + r*256;
        if (idx < PHB/16)
            __builtin_amdgcn_global_load_lds(
                (const __attribute__((address_space(1))) unsigned int*)(Asrc + (size_t)idx*16),
                (__attribute__((address_space(3))) unsigned int*)(&lds[0][idx*16]),
                16, 0, 0);
    }
    __syncthreads();

    f32x16 zf;
#pragma unroll
    for (int r = 0; r < 16; ++r) zf[r] = 0.f;

    for (int ph = 0; ph < 8; ++ph) {
        const int cur = ph & 1;
        if (ph < 7) {
            const char* src = Asrc + (size_t)(ph+1)*PHB;
#pragma unroll
            for (int r = 0; r < 5; ++r) {
                int idx = tid + r*256;
                if (idx < PHB/16)
                    __builtin_amdgcn_global_load_lds(
                        (const __attribute__((address_space(1))) unsigned int*)(src + (size_t)idx*16),
                        (__attribute__((address_space(3))) unsigned int*)(&lds[cur^1][idx*16]),
                        16, 0, 0);
            }
        }
#pragma unroll
        for (int kt2 = 0; kt2 < 2; ++kt2) {
            const int ktl = ph*2 + kt2;
            const char* ab = &lds[cur][kt2*KTB + l*16];
            bf16x8 A[9];                    // f = s*3 + q
#pragma unroll
            for (int f = 0; f < 9; ++f)
                A[f] = *(const bf16x8*)(ab + f*1024);

            f32x16 acc0, acc1;
            acc0 = __builtin_amdgcn_mfma_f32_32x32x16_bf16(A[0], Bf[0][0], zf, 0, 0, 0);
            acc1 = __builtin_amdgcn_mfma_f32_32x32x16_bf16(A[0], Bf[1][0], zf, 0, 0, 0);
#pragma unroll
            for (int s = 0; s < 3; ++s)
#pragma unroll
                for (int q = 0; q < 3; ++q) {
                    if (s == 0 && q == 0) continue;
                    const int f = s*3 + q;
                    acc0 = __builtin_amdgcn_mfma_f32_32x32x16_bf16(A[f], Bf[0][s], acc0, 0, 0, 0);
                    acc1 = __builtin_amdgcn_mfma_f32_32x32x16_bf16(A[f], Bf[1][s], acc1, 0, 0, 0);
                }
            // VALU-diet argmax: max3 tree (8 ops) + running (V,bkt) (3 ops)
            // + per-reg running maxes (16 v_max) for end-of-loop index recovery
#pragma unroll
            for (int i = 0; i < 2; ++i) {
                const f32x16& a = (i == 0) ? acc0 : acc1;
                float m0 = max3f(a[0],  a[1],  a[2]);
                float m1 = max3f(a[3],  a[4],  a[5]);
                float m2 = max3f(a[6],  a[7],  a[8]);
                float m3 = max3f(a[9],  a[10], a[11]);
                float m4 = max3f(a[12], a[13], a[14]);
                float m5 = max3f(m0, m1, a[15]);
                float m6 = max3f(m2, m3, m4);
                float t  = fmaxf(m5, m6);
                bkt[i] = (t > V[i]) ? ktl : bkt[i];
                V[i] = fmaxf(V[i], t);
#pragma unroll
                for (int r = 0; r < 16; ++r)
                    bv16[i][r] = fmaxf(bv16[i][r], a[r]);
            }
        }
        __syncthreads();
    }

    // epilogue: recover reg index (first r, row-ascending == r-ascending per h,
    // with bv16[r] == V), then cross-half merge
    const int h = l >> 5;
#pragma unroll
    for (int i = 0; i < 2; ++i) {
        int rb = 0;
#pragma unroll
        for (int r = 15; r >= 0; --r)
            rb = (bv16[i][r] == V[i]) ? r : rb;
        int kk = kg*512 + bkt[i]*32 + (rb & 3) + ((rb >> 2) << 3) + (h << 2);
        float v = V[i];
        float ov = __shfl_xor(v, 32);
        int   ok = __shfl_xor(kk, 32);
        if (ov > v || (ov == v && ok < kk)) { v = ov; kk = ok; }
        if (l < 32) {
            int pair = (pt0 + i)*32 + l;
            pval[(size_t)pair*NKG + kg] = v;
            pidx[(size_t)pair*NKG + kg] = kk;
        }
    }
}

// ---------- k3: combine 8 k-groups + LUT1 gather + reconstruct, 8 thr/b --------
// Thread j of b owns float4 lane j of the 32-wide row. The 8-way kg argmax is
// recomputed redundantly per lane from broadcast (same-cacheline) loads.
__global__ __launch_bounds__(256) void k3_final(
    const float* __restrict__ pval, const int* __restrict__ pidx,
    const float* __restrict__ LUT1, const float* __restrict__ p2vec,
    float* __restrict__ out) {
    int t = blockIdx.x * 256 + threadIdx.x;
    int b = t >> 3, j = t & 7;
    if (b >= B_TOT) return;
    float4 r = ((const float4*)(p2vec + (size_t)b*32))[j];
#pragma unroll
    for (int c = 0; c < 5; ++c) {
        size_t pair = (size_t)b*5 + c;
        const float4* pv4 = (const float4*)(pval + pair*NKG);
        const int4*   pi4 = (const int4*)(pidx + pair*NKG);
        float4 v0 = pv4[0], v1 = pv4[1];
        int4   i0 = pi4[0], i1 = pi4[1];
        float vv[8] = {v0.x, v0.y, v0.z, v0.w, v1.x, v1.y, v1.z, v1.w};
        int   ii[8] = {i0.x, i0.y, i0.z, i0.w, i1.x, i1.y, i1.z, i1.w};
        float bvv = vv[0]; int bk = ii[0];
#pragma unroll
        for (int q = 1; q < 8; ++q) {
            // q ascending == k ascending: ties keep smaller k via strict >
            if (vv[q] > bvv) { bvv = vv[q]; bk = ii[q]; }
        }
        float4 tl = ((const float4*)(LUT1 + ((size_t)c*4096 + bk)*32))[j];
        r.x += tl.x; r.y += tl.y; r.z += tl.z; r.w += tl.w;
    }
    ((float4*)(out + (size_t)b*32))[j] = r;
}

extern "C" void kernel_launch(void* const* d_in, const int* in_sizes, int n_in,
                              void* d_out, int out_size, void* d_ws, size_t ws_size,
                              hipStream_t stream) {
    const int*   x      = (const int*)d_in[0];
    const float* lenLUT = (const float*)d_in[1];
    const float* ipdLUT = (const float*)d_in[2];
    const float* S1     = (const float*)d_in[3];
    const float* H1     = (const float*)d_in[4];
    const float* T1     = (const float*)d_in[5];
    const float* LUT1   = (const float*)d_in[6];
    const float* S2     = (const float*)d_in[7];
    const float* H2     = (const float*)d_in[8];
    const float* T2     = (const float*)d_in[9];
    const float* LUT2   = (const float*)d_in[10];
    float* out = (float*)d_out;

    char* ws = (char*)d_ws;
    unsigned short* Abuf = (unsigned short*)ws;                        // 1.18 MB
    size_t off = (size_t)1152*1024;
    unsigned short* Bbuf = (unsigned short*)(ws + off);                // 7.86 MB
    off += (size_t)NPT32*1536*2;
    float* p2vec = (float*)(ws + off);                                 // 2.1 MB
    off += (size_t)B_TOT*32*4;
    float* pval  = (float*)(ws + off);                                 // 2.62 MB
    off += (size_t)NPAIR*NKG*4;
    int*   pidx  = (int*)(ws + off);                                   // 2.62 MB

    kfront<<<dim3(PREP_BLKS + SIGN_BLKS + EMBD_BLKS), dim3(256), 0, stream>>>(
        x, lenLUT, ipdLUT, S1, H1, T1, S2, H2, T2, LUT2, out, p2vec, Abuf, Bbuf);
    k2m<<<dim3(2560), dim3(256), 0, stream>>>(Abuf, Bbuf, pval, pidx);
    k3_final<<<dim3(B_TOT*8/256), dim3(256), 0, stream>>>(
        pval, pidx, LUT1, p2vec, out);
}

// Round 2
// 92.386 us; speedup vs baseline: 1.5355x; 1.5355x over previous
//
#include <hip/hip_runtime.h>

#define B_TOT 16384
#define NPAIR (B_TOT*5)        // 81920 (b,chunk) pairs
#define NPT32 (NPAIR/32)       // 2560 pair-tiles of 32 pairs
#define NKG   8                // k-groups of 16 k-tiles (512 k each)
#define KTPG  16               // k-tiles per group
#define KTB   9216             // bytes per A k-tile: 9 frags x 1KB
#define PHB   (2*KTB)          // 18432 B per phase (2 k-tiles)

// fused front-kernel grid split
#define PREP_BLKS 288          // 1152 prep-units / 4 per 256-thr block
#define SIGN_BLKS 320          // 81920 / 256
#define EMBD_BLKS 64           // 16384 / 256

typedef __attribute__((ext_vector_type(8))) short bf16x8;
typedef __attribute__((ext_vector_type(16))) float f32x16;

struct alignas(8) us4 { unsigned short x, y, z, w; };

__device__ inline unsigned short f2bf(float f) {
    unsigned u = __builtin_bit_cast(unsigned, f);
    unsigned r = u + 0x7fffu + ((u >> 16) & 1u);
    return (unsigned short)(r >> 16);
}
__device__ inline float bf2f(unsigned short b) {
    unsigned u = ((unsigned)b) << 16;
    return __builtin_bit_cast(float, u);
}
__device__ inline float max3f(float a, float b, float c) {
    return fmaxf(fmaxf(a, b), c);      // fuses to v_max3_f32
}

// ---------- fused front kernel: kprep + k1_signs + k1_embed --------------------
// Section A (bid < PREP_BLKS): H1 [45][4096] f32 -> Abuf bf16 3-split,
//   32x32x16-frag-major (verified layout). Block blk = kt*9 + s*3 + q : 1KB frag.
//   Lane l: row(k-vocab) = kt*32 + (l&31), h = l>>5;
//     elem j<4:  d = 16s + 4h + j ;  j>=4: d = 16s + 8 + 4h + (j-4). d>=45 -> 0.
// Section B: per-(b,c) sign computation -> Bbuf (chunk c uses only e[6c..6c+5]).
// Section C: per-b full embed -> ebd out + part-2 argmax -> p2vec.
__global__ __launch_bounds__(256) void kfront(
    const int* __restrict__ x,
    const float* __restrict__ lenLUT, const float* __restrict__ ipdLUT,
    const float* __restrict__ S1, const float* __restrict__ H1,
    const float* __restrict__ T1,
    const float* __restrict__ S2, const float* __restrict__ H2,
    const float* __restrict__ T2, const float* __restrict__ LUT2,
    float* __restrict__ out, float* __restrict__ p2vec,
    unsigned short* __restrict__ Abuf, unsigned short* __restrict__ Bbuf) {
    const int bid = blockIdx.x;
    const int tid = threadIdx.x;

    if (bid < PREP_BLKS) {
        // ---- kprep (4 prep-units of 64 lanes per block) ----
        int blk = bid * 4 + (tid >> 6);     // 0..1151
        int kt = blk / 9, rem = blk - kt*9;
        int s = rem / 3, q = rem - s*3;
        int l = tid & 63;
        int h = l >> 5;
        int row = kt*32 + (l & 31);
        unsigned short o[8];
#pragma unroll
        for (int j = 0; j < 8; ++j) {
            int d = 16*s + 4*h + ((j < 4) ? j : (j + 4));
            float v = (d < 45) ? H1[(size_t)d*4096 + row] : 0.f;
            unsigned short bb = 0;
            for (int qq = 0; qq <= q; ++qq) { bb = f2bf(v); v -= bf2f(bb); }  // q uniform per 64-group
            o[j] = bb;
        }
        unsigned short* dst = Abuf + (size_t)blk*512 + l*8;
        *(us4*)(dst)     = us4{o[0], o[1], o[2], o[3]};
        *(us4*)(dst + 4) = us4{o[4], o[5], o[6], o[7]};
        return;
    }

    if (bid < PREP_BLKS + SIGN_BLKS) {
        // ---- k1_signs: one thread per (b,c) pair, p = b*5 + c ----
        int p = (bid - PREP_BLKS) * 256 + tid;   // 0..81919
        int b = p / 5;
        int c = p - b * 5;
        int x0 = x[2*b], x1 = x[2*b+1];
        float e[6];
        const float2* l2 = (const float2*)(lenLUT + (size_t)x0*32 + 6*c);
        const float2* i2 = (const float2*)(ipdLUT + (size_t)x1*32 + 6*c);
#pragma unroll
        for (int t = 0; t < 3; ++t) {
            float2 a = l2[t], d = i2[t];
            e[2*t]   = a.x + d.x;
            e[2*t+1] = a.y + d.y;
        }
        unsigned short sg[48];
#pragma unroll
        for (int t = 0; t < 3; ++t) {
            int c15 = 3*c + t;
#pragma unroll
            for (int k = 0; k < 15; ++k) {
                float a = e[2*t] * S1[(2*c15)*15 + k] + e[2*t+1] * S1[(2*c15+1)*15 + k];
                a = a - T1[c15*15 + k];
                a = a - 1e-4f;
                sg[t*15+k] = (a > 0.f) ? (unsigned short)0x3F80u
                           : ((a < 0.f) ? (unsigned short)0xBF80u : (unsigned short)0);
            }
        }
        sg[45] = 0; sg[46] = 0; sg[47] = 0;
        int P = p >> 5, col = p & 31;
        unsigned short* base = Bbuf + (size_t)P*1536;
#pragma unroll
        for (int s = 0; s < 3; ++s) {
            unsigned short* blk = base + s*512;
            *(us4*)(blk + col*8)          = us4{sg[16*s+0],  sg[16*s+1],  sg[16*s+2],  sg[16*s+3]};
            *(us4*)(blk + col*8 + 4)      = us4{sg[16*s+8],  sg[16*s+9],  sg[16*s+10], sg[16*s+11]};
            *(us4*)(blk + (col+32)*8)     = us4{sg[16*s+4],  sg[16*s+5],  sg[16*s+6],  sg[16*s+7]};
            *(us4*)(blk + (col+32)*8 + 4) = us4{sg[16*s+12], sg[16*s+13], sg[16*s+14], sg[16*s+15]};
        }
        return;
    }

    // ---- k1_embed: per-b full embed row -> ebd out, part-2 -> p2vec ----
    {
        int b = (bid - PREP_BLKS - SIGN_BLKS) * 256 + tid;
        if (b >= B_TOT) return;
        int x0 = x[2*b], x1 = x[2*b+1];
        const float4* l4 = (const float4*)(lenLUT + (size_t)x0*32);
        const float4* i4 = (const float4*)(ipdLUT + (size_t)x1*32);
        float4* o4 = (float4*)(out + (size_t)B_TOT*32 + (size_t)b*32);
        float e30 = 0.f, e31 = 0.f;
#pragma unroll
        for (int j = 0; j < 8; ++j) {
            float4 a = l4[j], c = i4[j];
            float4 sv; sv.x=a.x+c.x; sv.y=a.y+c.y; sv.z=a.z+c.z; sv.w=a.w+c.w;
            o4[j] = sv;
            if (j == 7) { e30 = sv.z; e31 = sv.w; }
        }
        float sb[15];
#pragma unroll
        for (int k = 0; k < 15; ++k) {
            float bb = e30 * S2[k] + e31 * S2[15 + k];
            bb = bb - T2[k];
            sb[k] = (bb > 0.f) ? 1.f : -1.f;       // ==0 -> -1 per jnp.where
        }
        float best = -3.4e38f; int bi = 0;
#pragma unroll
        for (int k2 = 0; k2 < 16; ++k2) {
            float sc = 0.f;
#pragma unroll
            for (int d = 0; d < 15; ++d) sc = fmaf(sb[d], H2[d*16 + k2], sc);
            if (sc > best) { best = sc; bi = k2; }
        }
        const float4* lr = (const float4*)(LUT2 + (size_t)bi*32);
        float4* pv = (float4*)(p2vec + (size_t)b*32);
#pragma unroll
        for (int j = 0; j < 8; ++j) pv[j] = lr[j];
    }
}

// ---------- k2m: R8-verbatim (best measured: 78.7us; VGPR 84, no spills) ------
// Block = 4 waves x 2 pt = 8 pt, one k-eighth (16 k-tiles), 2-kt dbuf staging.
// kg = bid&7 -> XCD-pinned A slice.
// NOTE: launch_bounds(256,4) forces a 64-VGPR allocation -> scratch spills
// (WRITE_SIZE 41MB->203MB, k2m 78.7->142us). Keep (256,3).
__global__ __launch_bounds__(256, 3) void k2m(
    const unsigned short* __restrict__ Abuf,
    const unsigned short* __restrict__ Bbuf,
    float* __restrict__ pval, int* __restrict__ pidx) {
    const int bid = blockIdx.x;            // 0..2559
    const int kg = bid & 7;
    const int pg = bid >> 3;               // 0..319
    const int tid = threadIdx.x;
    const int w = tid >> 6, l = tid & 63;
    const int pt0 = pg*8 + w*2;

    __shared__ __align__(16) char lds[2][PHB];    // 2 x 18 KB

    bf16x8 Bf[2][3];
#pragma unroll
    for (int i = 0; i < 2; ++i)
#pragma unroll
        for (int s = 0; s < 3; ++s)
            Bf[i][s] = *(const bf16x8*)(Bbuf + ((size_t)(pt0+i)*3 + s)*512 + l*8);

    // per-pt state: per-reg running max (for index recovery), running (V, bkt)
    float bv16[2][16];
    float V[2] = {-3.4e38f, -3.4e38f};
    int bkt[2] = {0, 0};
#pragma unroll
    for (int i = 0; i < 2; ++i)
#pragma unroll
        for (int r = 0; r < 16; ++r) bv16[i][r] = -3.4e38f;

    const char* Asrc = (const char*)Abuf + (size_t)kg*KTPG*KTB;

    // stage phase 0
#pragma unroll
    for (int r = 0; r < 5; ++r) {
        int idx = tid + r*256;
        if (idx < PHB/16)
            __builtin_amdgcn_global_load_lds(
                (const __attribute__((address_space(1))) unsigned int*)(Asrc + (size_t)idx*16),
                (__attribute__((address_space(3))) unsigned int*)(&lds[0][idx*16]),
                16, 0, 0);
    }
    __syncthreads();

    f32x16 zf;
#pragma unroll
    for (int r = 0; r < 16; ++r) zf[r] = 0.f;

    for (int ph = 0; ph < 8; ++ph) {
        const int cur = ph & 1;
        if (ph < 7) {
            const char* src = Asrc + (size_t)(ph+1)*PHB;
#pragma unroll
            for (int r = 0; r < 5; ++r) {
                int idx = tid + r*256;
                if (idx < PHB/16)
                    __builtin_amdgcn_global_load_lds(
                        (const __attribute__((address_space(1))) unsigned int*)(src + (size_t)idx*16),
                        (__attribute__((address_space(3))) unsigned int*)(&lds[cur^1][idx*16]),
                        16, 0, 0);
            }
        }
#pragma unroll
        for (int kt2 = 0; kt2 < 2; ++kt2) {
            const int ktl = ph*2 + kt2;
            const char* ab = &lds[cur][kt2*KTB + l*16];
            bf16x8 A[9];                    // f = s*3 + q
#pragma unroll
            for (int f = 0; f < 9; ++f)
                A[f] = *(const bf16x8*)(ab + f*1024);

            f32x16 acc0, acc1;
            acc0 = __builtin_amdgcn_mfma_f32_32x32x16_bf16(A[0], Bf[0][0], zf, 0, 0, 0);
            acc1 = __builtin_amdgcn_mfma_f32_32x32x16_bf16(A[0], Bf[1][0], zf, 0, 0, 0);
#pragma unroll
            for (int s = 0; s < 3; ++s)
#pragma unroll
                for (int q = 0; q < 3; ++q) {
                    if (s == 0 && q == 0) continue;
                    const int f = s*3 + q;
                    acc0 = __builtin_amdgcn_mfma_f32_32x32x16_bf16(A[f], Bf[0][s], acc0, 0, 0, 0);
                    acc1 = __builtin_amdgcn_mfma_f32_32x32x16_bf16(A[f], Bf[1][s], acc1, 0, 0, 0);
                }
            // VALU-diet argmax: max3 tree (8 ops) + running (V,bkt) (3 ops)
            // + per-reg running maxes (16 v_max) for end-of-loop index recovery
#pragma unroll
            for (int i = 0; i < 2; ++i) {
                const f32x16& a = (i == 0) ? acc0 : acc1;
                float m0 = max3f(a[0],  a[1],  a[2]);
                float m1 = max3f(a[3],  a[4],  a[5]);
                float m2 = max3f(a[6],  a[7],  a[8]);
                float m3 = max3f(a[9],  a[10], a[11]);
                float m4 = max3f(a[12], a[13], a[14]);
                float m5 = max3f(m0, m1, a[15]);
                float m6 = max3f(m2, m3, m4);
                float t  = fmaxf(m5, m6);
                bkt[i] = (t > V[i]) ? ktl : bkt[i];
                V[i] = fmaxf(V[i], t);
#pragma unroll
                for (int r = 0; r < 16; ++r)
                    bv16[i][r] = fmaxf(bv16[i][r], a[r]);
            }
        }
        __syncthreads();
    }

    // epilogue: recover reg index (first r, row-ascending == r-ascending per h,
    // with bv16[r] == V), then cross-half merge
    const int h = l >> 5;
#pragma unroll
    for (int i = 0; i < 2; ++i) {
        int rb = 0;
#pragma unroll
        for (int r = 15; r >= 0; --r)
            rb = (bv16[i][r] == V[i]) ? r : rb;
        int kk = kg*512 + bkt[i]*32 + (rb & 3) + ((rb >> 2) << 3) + (h << 2);
        float v = V[i];
        float ov = __shfl_xor(v, 32);
        int   ok = __shfl_xor(kk, 32);
        if (ov > v || (ov == v && ok < kk)) { v = ov; kk = ok; }
        if (l < 32) {
            int pair = (pt0 + i)*32 + l;
            pval[(size_t)pair*NKG + kg] = v;
            pidx[(size_t)pair*NKG + kg] = kk;
        }
    }
}

// ---------- k3: combine 8 k-groups + LUT1 gather + reconstruct, 8 thr/b --------
// Thread j of b owns float4 lane j of the 32-wide row. The 8-way kg argmax is
// recomputed redundantly per lane from broadcast (same-cacheline) loads.
__global__ __launch_bounds__(256) void k3_final(
    const float* __restrict__ pval, const int* __restrict__ pidx,
    const float* __restrict__ LUT1, const float* __restrict__ p2vec,
    float* __restrict__ out) {
    int t = blockIdx.x * 256 + threadIdx.x;
    int b = t >> 3, j = t & 7;
    if (b >= B_TOT) return;
    float4 r = ((const float4*)(p2vec + (size_t)b*32))[j];
#pragma unroll
    for (int c = 0; c < 5; ++c) {
        size_t pair = (size_t)b*5 + c;
        const float4* pv4 = (const float4*)(pval + pair*NKG);
        const int4*   pi4 = (const int4*)(pidx + pair*NKG);
        float4 v0 = pv4[0], v1 = pv4[1];
        int4   i0 = pi4[0], i1 = pi4[1];
        float vv[8] = {v0.x, v0.y, v0.z, v0.w, v1.x, v1.y, v1.z, v1.w};
        int   ii[8] = {i0.x, i0.y, i0.z, i0.w, i1.x, i1.y, i1.z, i1.w};
        float bvv = vv[0]; int bk = ii[0];
#pragma unroll
        for (int q = 1; q < 8; ++q) {
            // q ascending == k ascending: ties keep smaller k via strict >
            if (vv[q] > bvv) { bvv = vv[q]; bk = ii[q]; }
        }
        float4 tl = ((const float4*)(LUT1 + ((size_t)c*4096 + bk)*32))[j];
        r.x += tl.x; r.y += tl.y; r.z += tl.z; r.w += tl.w;
    }
    ((float4*)(out + (size_t)b*32))[j] = r;
}

extern "C" void kernel_launch(void* const* d_in, const int* in_sizes, int n_in,
                              void* d_out, int out_size, void* d_ws, size_t ws_size,
                              hipStream_t stream) {
    const int*   x      = (const int*)d_in[0];
    const float* lenLUT = (const float*)d_in[1];
    const float* ipdLUT = (const float*)d_in[2];
    const float* S1     = (const float*)d_in[3];
    const float* H1     = (const float*)d_in[4];
    const float* T1     = (const float*)d_in[5];
    const float* LUT1   = (const float*)d_in[6];
    const float* S2     = (const float*)d_in[7];
    const float* H2     = (const float*)d_in[8];
    const float* T2     = (const float*)d_in[9];
    const float* LUT2   = (const float*)d_in[10];
    float* out = (float*)d_out;

    char* ws = (char*)d_ws;
    unsigned short* Abuf = (unsigned short*)ws;                        // 1.18 MB
    size_t off = (size_t)1152*1024;
    unsigned short* Bbuf = (unsigned short*)(ws + off);                // 7.86 MB
    off += (size_t)NPT32*1536*2;
    float* p2vec = (float*)(ws + off);                                 // 2.1 MB
    off += (size_t)B_TOT*32*4;
    float* pval  = (float*)(ws + off);                                 // 2.62 MB
    off += (size_t)NPAIR*NKG*4;
    int*   pidx  = (int*)(ws + off);                                   // 2.62 MB

    kfront<<<dim3(PREP_BLKS + SIGN_BLKS + EMBD_BLKS), dim3(256), 0, stream>>>(
        x, lenLUT, ipdLUT, S1, H1, T1, S2, H2, T2, LUT2, out, p2vec, Abuf, Bbuf);
    k2m<<<dim3(2560), dim3(256), 0, stream>>>(Abuf, Bbuf, pval, pidx);
    k3_final<<<dim3(B_TOT*8/256), dim3(256), 0, stream>>>(
        pval, pidx, LUT1, p2vec, out);
}